// Round 10
// baseline (229.351 us; speedup 1.0000x reference)
//
#include <hip/hip_runtime.h>
#include <hip/hip_bf16.h>
#include <hip/hip_cooperative_groups.h>

namespace cg = cooperative_groups;

#define BB   4
#define NN   10000
#define EE   160000
#define FIN  256
#define HH   8
#define FO   32
#define CC   256            // H*FO
#define BN   40000          // B*N
#define BE   640000         // B*E
#define NB   157            // ceil(BN/256)

typedef __attribute__((ext_vector_type(8))) __bf16 bf16x8;
typedef __attribute__((ext_vector_type(8))) unsigned short u16x8;
typedef __attribute__((ext_vector_type(4))) float  f32x4;

__device__ __forceinline__ float bf2f(unsigned short u) {
    unsigned int v = ((unsigned int)u) << 16;
    return __uint_as_float(v);
}
__device__ __forceinline__ unsigned short f2bf(float f) {
    unsigned int u = __float_as_uint(f);
    u += 0x7fffu + ((u >> 16) & 1u);   // round-to-nearest-even
    return (unsigned short)(u >> 16);
}
// pack two f32 -> two bf16 (RNE) in one instruction
__device__ __forceinline__ unsigned int cvtpk(float lo, float hi) {
    unsigned int r;
    asm volatile("v_cvt_pk_bf16_f32 %0, %1, %2" : "=v"(r) : "v"(lo), "v"(hi));
    return r;
}

__device__ __forceinline__ void cvt8(const float* __restrict__ src,
                                     unsigned short* __restrict__ dst, int i)
{
    const float4* s = (const float4*)src + (size_t)i * 2;
    float4 v0 = s[0], v1 = s[1];
    float f[8] = {v0.x, v0.y, v0.z, v0.w, v1.x, v1.y, v1.z, v1.w};
    union { unsigned short u[8]; uint4 q; } o;
#pragma unroll
    for (int j = 0; j < 8; ++j) o.u[j] = f2bf(f[j]);
    ((uint4*)dst)[i] = o.q;
}

// 256-thread block exclusive scan (int). lds4 is a __shared__ int[4].
__device__ __forceinline__ int block_excl_scan_256(int v, int t, int* lds4,
                                                   int* total)
{
    int lane = t & 63, wid = t >> 6;
    int incl = v;
#pragma unroll
    for (int off = 1; off < 64; off <<= 1) {
        int u = __shfl_up(incl, off);
        if (lane >= off) incl += u;
    }
    if (lane == 63) lds4[wid] = incl;
    __syncthreads();
    int w0 = lds4[0], w1 = lds4[1], w2 = lds4[2], w3 = lds4[3];
    int woff = (wid > 0 ? w0 : 0) + (wid > 1 ? w1 : 0) + (wid > 2 ? w2 : 0);
    *total = w0 + w1 + w2 + w3;
    return woff + incl - v;
}

// ---------------------------------------------------------------------------
// Cooperative CSR kernel: zero-deg + W cvt | histogram | block sums |
// cursor fill | edge scatter — one launch, grid.sync between phases.
// 157 blocks x 256 threads (all co-resident; <= 256 CUs).
// ---------------------------------------------------------------------------
__global__ __launch_bounds__(256) void k_csr(
    const float* __restrict__ Wm, const int* __restrict__ ei,
    const float* __restrict__ mask, unsigned short* __restrict__ wb,
    int* __restrict__ deg, int* __restrict__ bsum,
    int* __restrict__ cursor, int* __restrict__ esrc)
{
    cg::grid_group grid = cg::this_grid();
    __shared__ int w4[4];
    __shared__ int w4a[4];
    __shared__ int w4b[4];
    const int t = threadIdx.x, bid = blockIdx.x;
    const int gtid = bid * 256 + t;              // < 40192

    // ---- P0: zero deg + W->bf16 cvt
    if (gtid < BN) deg[gtid] = 0;
    if (gtid < CC * FIN / 8) cvt8(Wm, wb, gtid);
    grid.sync();

    // ---- P1: deg histogram (4 int4-groups = 16 edges per thread)
#pragma unroll
    for (int g = 0; g < 4; ++g) {
        int i = g * (NB * 256) + gtid;
        if (i < BE / 4) {
            int e0 = i * 4;
            int b  = e0 / EE;                    // EE%4==0 -> uniform in int4
            int le = e0 - b * EE;
            int4 tq = *(const int4*)(ei + (size_t)b * 2 * EE + EE + le);
            int base = b * NN;
            atomicAdd(&deg[tq.x + base], 1);
            atomicAdd(&deg[tq.y + base], 1);
            atomicAdd(&deg[tq.z + base], 1);
            atomicAdd(&deg[tq.w + base], 1);
        }
    }
    grid.sync();

    // ---- P2: per-block sums of deg (block b covers nodes [b*256, b*256+256))
    int v = (gtid < BN) ? deg[gtid] : 0;
    {
        int vv = v;
#pragma unroll
        for (int off = 32; off >= 1; off >>= 1) vv += __shfl_xor(vv, off);
        if ((t & 63) == 0) w4[t >> 6] = vv;
        __syncthreads();
        if (t == 0) bsum[bid] = w4[0] + w4[1] + w4[2] + w4[3];
    }
    grid.sync();

    // ---- P3: cursor fill (block offset = sum bsum[0..bid))
    {
        int bv = (t < bid) ? bsum[t] : 0;        // bid <= 156 < 256
#pragma unroll
        for (int off = 32; off >= 1; off >>= 1) bv += __shfl_xor(bv, off);
        if ((t & 63) == 0) w4a[t >> 6] = bv;
        __syncthreads();
        int boff = w4a[0] + w4a[1] + w4a[2] + w4a[3];
        int total;
        int excl = block_excl_scan_256(v, t, w4b, &total);
        if (gtid < BN) cursor[gtid] = boff + excl;
    }
    grid.sync();

    // ---- P4: edge scatter (claim slot, store src | mask-bit)
#pragma unroll
    for (int g = 0; g < 4; ++g) {
        int i = g * (NB * 256) + gtid;
        if (i < BE / 4) {
            int e0 = i * 4;
            int b  = e0 / EE;
            int le = e0 - b * EE;
            const int* eb = ei + (size_t)b * 2 * EE;
            int4   sq = *(const int4*)(eb + le);
            int4   tq = *(const int4*)(eb + EE + le);
            float4 mq = *(const float4*)(mask + e0);
            int base = b * NN;
            int p0 = atomicAdd(&cursor[tq.x + base], 1);
            int p1 = atomicAdd(&cursor[tq.y + base], 1);
            int p2 = atomicAdd(&cursor[tq.z + base], 1);
            int p3 = atomicAdd(&cursor[tq.w + base], 1);
            esrc[p0] = (sq.x + base) | (mq.x > 0.f ? 0 : (int)0x80000000);
            esrc[p1] = (sq.y + base) | (mq.y > 0.f ? 0 : (int)0x80000000);
            esrc[p2] = (sq.z + base) | (mq.z > 0.f ? 0 : (int)0x80000000);
            esrc[p3] = (sq.w + base) | (mq.w > 0.f ? 0 : (int)0x80000000);
        }
    }
}

// ---------------------------------------------------------------------------
// Kernel 1: proj = x @ Wb^T via MFMA bf16 (128x128 tile, BK=64, 4 waves)
// + fused score epilogue through LDS: each wave dumps its 64x64 f32 quadrant
// as swizzled bf16 into the freed As/Bs space, reads back one row per lane,
// and dots 32-col head slices with a_src/a_trg (staged in LDS).
// ---------------------------------------------------------------------------
__global__ __launch_bounds__(256) void k_gemm(
    const float* __restrict__ x, const unsigned short* __restrict__ wb,
    const float* __restrict__ a_src, const float* __restrict__ a_trg,
    unsigned short* __restrict__ proj, float* __restrict__ ssrc,
    float* __restrict__ strg)
{
    __shared__ alignas(16) unsigned short S[2][128 * 64];   // As | Bs, 32 KB
    __shared__ float sa[CC], sb[CC];
    unsigned short* As = S[0];
    unsigned short* Bs = S[1];

    const int t    = threadIdx.x;
    const int lane = t & 63;
    const int wid  = t >> 6;
    const int wr   = wid >> 1, wc = wid & 1;
    const int bm   = blockIdx.x >> 1;
    const int bn   = blockIdx.x & 1;
    const int row0 = bm * 128, col0 = bn * 128;

    sa[t] = a_src[t];          // CC == blockDim
    sb[t] = a_trg[t];

    const int srow = t >> 3;            // 0..31
    const int scol = (t & 7) * 8;

    f32x4 acc[4][4] = {};

    for (int kt = 0; kt < 4; ++kt) {
        const int k0 = kt * 64;
#pragma unroll
        for (int p = 0; p < 4; ++p) {
            int tr = p * 32 + srow;                       // tile row 0..127
            int swz = (tr & 7) << 3;
            int gra = row0 + tr; if (gra > BN - 1) gra = BN - 1;  // M-tail
            // A: f32 load + cvt_pk + swizzled LDS write
            const float4* xa = (const float4*)(x + (size_t)gra * FIN + k0 + scol);
            float4 v0 = xa[0], v1 = xa[1];
            uint4 w;
            w.x = cvtpk(v0.x, v0.y);
            w.y = cvtpk(v0.z, v0.w);
            w.z = cvtpk(v1.x, v1.y);
            w.w = cvtpk(v1.z, v1.w);
            *(uint4*)&As[tr * 64 + (scol ^ swz)] = w;
            // B: direct-to-LDS from pre-swizzled source
            const unsigned short* gb = wb + (size_t)(col0 + tr) * FIN + k0 + (scol ^ swz);
            __builtin_amdgcn_global_load_lds(
                (const __attribute__((address_space(1))) void*)gb,
                (__attribute__((address_space(3))) void*)&Bs[p * 2048 + t * 8],
                16, 0, 0);
        }
        __syncthreads();

#pragma unroll
        for (int kk = 0; kk < 2; ++kk) {
            bf16x8 af[4], bfr[4];
#pragma unroll
            for (int m = 0; m < 4; ++m) {
                int row = wr * 64 + m * 16 + (lane & 15);
                int col = (kk * 32 + (lane >> 4) * 8) ^ ((row & 7) << 3);
                af[m] = *(const bf16x8*)&As[row * 64 + col];
            }
#pragma unroll
            for (int n = 0; n < 4; ++n) {
                int row = wc * 64 + n * 16 + (lane & 15);
                int col = (kk * 32 + (lane >> 4) * 8) ^ ((row & 7) << 3);
                bfr[n] = *(const bf16x8*)&Bs[row * 64 + col];
            }
#pragma unroll
            for (int m = 0; m < 4; ++m)
#pragma unroll
                for (int n = 0; n < 4; ++n)
                    acc[m][n] = __builtin_amdgcn_mfma_f32_16x16x32_bf16(
                        af[m], bfr[n], acc[m][n], 0, 0, 0);
        }
        __syncthreads();
    }

    // ---- C write (bf16 proj)
    const int rbase = row0 + wr * 64 + (lane >> 4) * 4;
    const int cbase = col0 + wc * 64 + (lane & 15);
#pragma unroll
    for (int m = 0; m < 4; ++m)
#pragma unroll
        for (int n = 0; n < 4; ++n)
#pragma unroll
            for (int j = 0; j < 4; ++j) {
                int r = rbase + m * 16 + j;
                int c = cbase + n * 16;
                if (r < BN) proj[(size_t)r * CC + c] = f2bf(acc[m][n][j]);
            }

    // ---- fused score epilogue (As/Bs are free: all waves passed last sync)
    unsigned short* Ew = &S[0][0] + wid * 4096;   // this wave's 64x64 bf16
#pragma unroll
    for (int m = 0; m < 4; ++m)
#pragma unroll
        for (int n = 0; n < 4; ++n)
#pragma unroll
            for (int j = 0; j < 4; ++j) {
                int i = m * 16 + (lane >> 4) * 4 + j;     // local row
                int c = n * 16 + (lane & 15);             // local col
                int gs = ((c >> 3) + (i & 7)) & 7;        // granule swizzle
                Ew[i * 64 + gs * 8 + (c & 7)] = f2bf(acc[m][n][j]);
            }
    __syncthreads();

    {
        int i = lane;                                     // local row = lane
        float vs0 = 0.f, vs1 = 0.f, vt0 = 0.f, vt1 = 0.f;
        const int cb = bn * 128 + wc * 64;                // global col base
#pragma unroll
        for (int g = 0; g < 8; ++g) {
            int gs = (g + (i & 7)) & 7;
            u16x8 v = *(const u16x8*)&Ew[i * 64 + gs * 8];
#pragma unroll
            for (int e = 0; e < 8; ++e) {
                float f = bf2f(v[e]);
                int c = g * 8 + e;                        // compile-time
                float A = sa[cb + c], B = sb[cb + c];     // LDS broadcast
                if (c < 32) { vs0 += f * A; vt0 += f * B; }
                else        { vs1 += f * A; vt1 += f * B; }
            }
        }
        int r  = row0 + wr * 64 + i;
        int h0 = bn * 4 + wc * 2;
        if (r < BN) {
            ssrc[(size_t)r * HH + h0]     = vs0;
            ssrc[(size_t)r * HH + h0 + 1] = vs1;
            strg[(size_t)r * HH + h0]     = vt0;
            strg[(size_t)r * HH + h0 + 1] = vt1;
        }
    }
}

// ---------------------------------------------------------------------------
// Kernel D: one wave per target node, 8 edges/step + depth-2 prefetch of the
// next group's esrc/ssrc chain. Lane l owns exp for (edge l&7, head l>>3);
// __shfl distributes. Own-lane den + 3-shuffle reduce.
// ---------------------------------------------------------------------------
__global__ __launch_bounds__(256) void k_gather(
    const int* __restrict__ cursor, const int* __restrict__ esrc,
    const float* __restrict__ ssrc, const float* __restrict__ strg,
    const unsigned short* __restrict__ proj, const float* __restrict__ bias,
    float* __restrict__ out)
{
    int gid  = blockIdx.x * 256 + threadIdx.x;
    int node = gid >> 6;
    int lane = gid & 63;
    if (node >= BN) return;
    int h  = lane >> 3;
    int el = lane & 7;
    int hb = lane & 56;
    float st = strg[(size_t)node * HH + h];
    int lo = node ? cursor[node - 1] : 0;
    int hi = cursor[node];

    float acc0 = 0.f, acc1 = 0.f, acc2 = 0.f, acc3 = 0.f, deno = 0.f;

    // prologue: group 0's chain
    int  i0 = lo + el;
    bool v0 = i0 < hi;
    int  sv = v0 ? esrc[i0] : 0;
    int  s  = sv & 0x7fffffff;
    float f = ssrc[(size_t)s * HH + h];

    for (int p = lo; p < hi; p += 8) {
        int  i1 = p + 8 + el;
        bool v1 = i1 < hi;
        int  svn = v1 ? esrc[i1] : 0;
        float fn = ssrc[(size_t)(svn & 0x7fffffff) * HH + h];

        float c = f + st;
        c = c > 0.f ? c : 0.2f * c;                // leaky_relu(0.2)
        float ex = (v0 && sv >= 0) ? __expf(c) : 0.f;
        deno += ex;                                 // own-lane edge only

#pragma unroll
        for (int e = 0; e < 8; ++e) {
            float ee = __shfl(ex, e | hb);          // (edge e, this head)
            int   se = __shfl(s, e);
            ushort4 q = ((const ushort4*)(proj + (size_t)se * CC))[lane];
            acc0 += bf2f(q.x) * ee;
            acc1 += bf2f(q.y) * ee;
            acc2 += bf2f(q.z) * ee;
            acc3 += bf2f(q.w) * ee;
        }
        sv = svn; s = svn & 0x7fffffff; f = fn; v0 = v1;
    }

#pragma unroll
    for (int off = 1; off < 8; off <<= 1) deno += __shfl_xor(deno, off);

    float inv = 1.f / (deno + 1e-16f);
    float4 bv = ((const float4*)bias)[lane];
    float o0 = acc0 * inv + bv.x, o1 = acc1 * inv + bv.y;
    float o2 = acc2 * inv + bv.z, o3 = acc3 * inv + bv.w;
    o0 = o0 > 0.f ? o0 : __expf(o0) - 1.f;
    o1 = o1 > 0.f ? o1 : __expf(o1) - 1.f;
    o2 = o2 > 0.f ? o2 : __expf(o2) - 1.f;
    o3 = o3 > 0.f ? o3 : __expf(o3) - 1.f;
    ((float4*)(out + (size_t)node * CC))[lane] = make_float4(o0, o1, o2, o3);
}

// ---------------------------------------------------------------------------
extern "C" void kernel_launch(void* const* d_in, const int* in_sizes, int n_in,
                              void* d_out, int out_size, void* d_ws, size_t ws_size,
                              hipStream_t stream)
{
    const float* x     = (const float*)d_in[0];
    const int*   ei    = (const int*)  d_in[1];
    const float* mask  = (const float*)d_in[2];
    const float* Wm    = (const float*)d_in[3];
    const float* a_src = (const float*)d_in[4];
    const float* a_trg = (const float*)d_in[5];
    const float* bias  = (const float*)d_in[6];
    float* out = (float*)d_out;

    char* ws = (char*)d_ws;
    size_t off = 0;
    unsigned short* wb = (unsigned short*)(ws + off); off += (size_t)CC * FIN * 2; //  0.13 MB
    unsigned short* proj = (unsigned short*)(ws + off); off += (size_t)BN * CC * 2;// 20.48 MB
    float* ssrc = (float*)(ws + off); off += (size_t)BN * HH * 4;                  //  1.28 MB
    float* strg = (float*)(ws + off); off += (size_t)BN * HH * 4;                  //  1.28 MB
    int*   bsum = (int*)  (ws + off); off += 256 * 4;
    int*   deg    = (int*)(ws + off); off += (size_t)BN * 4;                       //  0.16 MB
    int*   cursor = (int*)(ws + off); off += (size_t)BN * 4;                       //  0.16 MB
    int*   esrc   = (int*)(ws + off); off += (size_t)(BE + 64) * 4;                //  2.56 MB

    void* args[] = {(void*)&Wm, (void*)&ei, (void*)&mask, (void*)&wb,
                    (void*)&deg, (void*)&bsum, (void*)&cursor, (void*)&esrc};
    hipLaunchCooperativeKernel((void*)k_csr, dim3(NB), dim3(256), args, 0, stream);

    k_gemm <<<((BN + 127) / 128) * 2, 256, 0, stream>>>(x, wb, a_src, a_trg,
                                                        proj, ssrc, strg);
    k_gather<<<(BN * 64) / 256, 256, 0, stream>>>(cursor, esrc, ssrc, strg,
                                                  proj, bias, out);
}

// Round 11
// 151.387 us; speedup vs baseline: 1.5150x; 1.5150x over previous
//
#include <hip/hip_runtime.h>
#include <hip/hip_bf16.h>

#define BB   4
#define NN   10000
#define EE   160000
#define FIN  256
#define HH   8
#define FO   32
#define CC   256            // H*FO
#define BN   40000          // B*N
#define BE   640000         // B*E
#define NB   157            // ceil(BN/256)

#define WCVT 32             // CC*FIN/8/256 blocks for W cvt
#define CNTB 625            // BE/4/256 blocks for histogram

typedef __attribute__((ext_vector_type(8))) __bf16 bf16x8;
typedef __attribute__((ext_vector_type(8))) unsigned short u16x8;
typedef __attribute__((ext_vector_type(4))) float  f32x4;

__device__ __forceinline__ float bf2f(unsigned short u) {
    unsigned int v = ((unsigned int)u) << 16;
    return __uint_as_float(v);
}
__device__ __forceinline__ unsigned short f2bf(float f) {
    unsigned int u = __float_as_uint(f);
    u += 0x7fffu + ((u >> 16) & 1u);   // round-to-nearest-even
    return (unsigned short)(u >> 16);
}
// pack two f32 -> two bf16 (RNE) in one instruction
__device__ __forceinline__ unsigned int cvtpk(float lo, float hi) {
    unsigned int r;
    asm volatile("v_cvt_pk_bf16_f32 %0, %1, %2" : "=v"(r) : "v"(lo), "v"(hi));
    return r;
}

__device__ __forceinline__ void cvt8(const float* __restrict__ src,
                                     unsigned short* __restrict__ dst, int i)
{
    const float4* s = (const float4*)src + (size_t)i * 2;
    float4 v0 = s[0], v1 = s[1];
    float f[8] = {v0.x, v0.y, v0.z, v0.w, v1.x, v1.y, v1.z, v1.w};
    union { unsigned short u[8]; uint4 q; } o;
#pragma unroll
    for (int j = 0; j < 8; ++j) o.u[j] = f2bf(f[j]);
    ((uint4*)dst)[i] = o.q;
}

// 256-thread block exclusive scan (int). lds4 is a __shared__ int[4].
__device__ __forceinline__ int block_excl_scan_256(int v, int t, int* lds4,
                                                   int* total)
{
    int lane = t & 63, wid = t >> 6;
    int incl = v;
#pragma unroll
    for (int off = 1; off < 64; off <<= 1) {
        int u = __shfl_up(incl, off);
        if (lane >= off) incl += u;
    }
    if (lane == 63) lds4[wid] = incl;
    __syncthreads();
    int w0 = lds4[0], w1 = lds4[1], w2 = lds4[2], w3 = lds4[3];
    int woff = (wid > 0 ? w0 : 0) + (wid > 1 ? w1 : 0) + (wid > 2 ? w2 : 0);
    *total = w0 + w1 + w2 + w3;
    return woff + incl - v;
}

// ---------------------------------------------------------------------------
// Kernel P: W->bf16 cvt + deg histogram (4 edges/thread, int4).
// ---------------------------------------------------------------------------
__global__ __launch_bounds__(256) void k_prep(
    const float* __restrict__ Wm, const int* __restrict__ ei,
    unsigned short* __restrict__ wb, int* __restrict__ deg)
{
    int blk = blockIdx.x, t = threadIdx.x;
    if (blk < WCVT) {
        cvt8(Wm, wb, blk * 256 + t);
    } else {
        int i = (blk - WCVT) * 256 + t;             // 4 edges per thread
        int e0 = i * 4;
        int b  = e0 / EE;
        int le = e0 - b * EE;
        int4 tq = *(const int4*)(ei + (size_t)b * 2 * EE + EE + le);
        int base = b * NN;
        atomicAdd(&deg[tq.x + base], 1);
        atomicAdd(&deg[tq.y + base], 1);
        atomicAdd(&deg[tq.z + base], 1);
        atomicAdd(&deg[tq.w + base], 1);
    }
}

// ---------------------------------------------------------------------------
// Kernel 1: proj = x @ Wb^T via MFMA bf16 (128x128 tile, BK=64, 4 waves)
// + fused score epilogue through LDS (validated in R10): each wave dumps its
// 64x64 f32 quadrant as swizzled bf16 into the freed As/Bs space, reads back
// one row per lane, dots 32-col head slices with a_src/a_trg.
// ---------------------------------------------------------------------------
__global__ __launch_bounds__(256) void k_gemm(
    const float* __restrict__ x, const unsigned short* __restrict__ wb,
    const float* __restrict__ a_src, const float* __restrict__ a_trg,
    unsigned short* __restrict__ proj, float* __restrict__ ssrc,
    float* __restrict__ strg)
{
    __shared__ alignas(16) unsigned short S[2][128 * 64];   // As | Bs, 32 KB
    __shared__ float sa[CC], sb[CC];
    unsigned short* As = S[0];
    unsigned short* Bs = S[1];

    const int t    = threadIdx.x;
    const int lane = t & 63;
    const int wid  = t >> 6;
    const int wr   = wid >> 1, wc = wid & 1;
    const int bm   = blockIdx.x >> 1;
    const int bn   = blockIdx.x & 1;
    const int row0 = bm * 128, col0 = bn * 128;

    sa[t] = a_src[t];          // CC == blockDim
    sb[t] = a_trg[t];

    const int srow = t >> 3;            // 0..31
    const int scol = (t & 7) * 8;

    f32x4 acc[4][4] = {};

    for (int kt = 0; kt < 4; ++kt) {
        const int k0 = kt * 64;
#pragma unroll
        for (int p = 0; p < 4; ++p) {
            int tr = p * 32 + srow;                       // tile row 0..127
            int swz = (tr & 7) << 3;
            int gra = row0 + tr; if (gra > BN - 1) gra = BN - 1;  // M-tail
            // A: f32 load + cvt_pk + swizzled LDS write
            const float4* xa = (const float4*)(x + (size_t)gra * FIN + k0 + scol);
            float4 v0 = xa[0], v1 = xa[1];
            uint4 w;
            w.x = cvtpk(v0.x, v0.y);
            w.y = cvtpk(v0.z, v0.w);
            w.z = cvtpk(v1.x, v1.y);
            w.w = cvtpk(v1.z, v1.w);
            *(uint4*)&As[tr * 64 + (scol ^ swz)] = w;
            // B: direct-to-LDS from pre-swizzled source
            const unsigned short* gb = wb + (size_t)(col0 + tr) * FIN + k0 + (scol ^ swz);
            __builtin_amdgcn_global_load_lds(
                (const __attribute__((address_space(1))) void*)gb,
                (__attribute__((address_space(3))) void*)&Bs[p * 2048 + t * 8],
                16, 0, 0);
        }
        __syncthreads();

#pragma unroll
        for (int kk = 0; kk < 2; ++kk) {
            bf16x8 af[4], bfr[4];
#pragma unroll
            for (int m = 0; m < 4; ++m) {
                int row = wr * 64 + m * 16 + (lane & 15);
                int col = (kk * 32 + (lane >> 4) * 8) ^ ((row & 7) << 3);
                af[m] = *(const bf16x8*)&As[row * 64 + col];
            }
#pragma unroll
            for (int n = 0; n < 4; ++n) {
                int row = wc * 64 + n * 16 + (lane & 15);
                int col = (kk * 32 + (lane >> 4) * 8) ^ ((row & 7) << 3);
                bfr[n] = *(const bf16x8*)&Bs[row * 64 + col];
            }
#pragma unroll
            for (int m = 0; m < 4; ++m)
#pragma unroll
                for (int n = 0; n < 4; ++n)
                    acc[m][n] = __builtin_amdgcn_mfma_f32_16x16x32_bf16(
                        af[m], bfr[n], acc[m][n], 0, 0, 0);
        }
        __syncthreads();
    }

    // ---- C write (bf16 proj)
    const int rbase = row0 + wr * 64 + (lane >> 4) * 4;
    const int cbase = col0 + wc * 64 + (lane & 15);
#pragma unroll
    for (int m = 0; m < 4; ++m)
#pragma unroll
        for (int n = 0; n < 4; ++n)
#pragma unroll
            for (int j = 0; j < 4; ++j) {
                int r = rbase + m * 16 + j;
                int c = cbase + n * 16;
                if (r < BN) proj[(size_t)r * CC + c] = f2bf(acc[m][n][j]);
            }

    // ---- fused score epilogue (As/Bs free after last sync)
    unsigned short* Ew = &S[0][0] + wid * 4096;   // this wave's 64x64 bf16
#pragma unroll
    for (int m = 0; m < 4; ++m)
#pragma unroll
        for (int n = 0; n < 4; ++n)
#pragma unroll
            for (int j = 0; j < 4; ++j) {
                int i = m * 16 + (lane >> 4) * 4 + j;     // local row
                int c = n * 16 + (lane & 15);             // local col
                int gs = ((c >> 3) + (i & 7)) & 7;        // granule swizzle
                Ew[i * 64 + gs * 8 + (c & 7)] = f2bf(acc[m][n][j]);
            }
    __syncthreads();

    {
        int i = lane;                                     // local row = lane
        float vs0 = 0.f, vs1 = 0.f, vt0 = 0.f, vt1 = 0.f;
        const int cb = bn * 128 + wc * 64;                // global col base
#pragma unroll
        for (int g = 0; g < 8; ++g) {
            int gs = (g + (i & 7)) & 7;
            u16x8 v = *(const u16x8*)&Ew[i * 64 + gs * 8];
#pragma unroll
            for (int e = 0; e < 8; ++e) {
                float f = bf2f(v[e]);
                int c = g * 8 + e;                        // compile-time
                float A = sa[cb + c], B = sb[cb + c];     // LDS broadcast
                if (c < 32) { vs0 += f * A; vt0 += f * B; }
                else        { vs1 += f * A; vt1 += f * B; }
            }
        }
        int r  = row0 + wr * 64 + i;
        int h0 = bn * 4 + wc * 2;
        if (r < BN) {
            ssrc[(size_t)r * HH + h0]     = vs0;
            ssrc[(size_t)r * HH + h0 + 1] = vs1;
            strg[(size_t)r * HH + h0]     = vt0;
            strg[(size_t)r * HH + h0 + 1] = vt1;
        }
    }
}

// ---------------------------------------------------------------------------
// Kernel S: single-pass scan (windowed decoupled look-back) -> cursor.
// st[bid] = (flag<<32)|value; flag: 0 pending, 1 aggregate, 2 prefix.
// 157 blocks (< CU count, all co-resident); look-back only reads lower ids.
// ---------------------------------------------------------------------------
__global__ __launch_bounds__(256) void k_scanfill(
    const int* __restrict__ deg, unsigned long long* __restrict__ st,
    int* __restrict__ cursor)
{
    __shared__ int w4b[4];
    __shared__ int sh_boff;
    const int t = threadIdx.x, bid = blockIdx.x;
    const int i = bid * 256 + t;
    int v = (i < BN) ? deg[i] : 0;

    int total;
    int excl = block_excl_scan_256(v, t, w4b, &total);

    if (t < 64) {
        if (t == 0) {
            unsigned long long pub =
                ((bid == 0 ? 2ull : 1ull) << 32) | (unsigned int)total;
            __hip_atomic_store(&st[bid], pub, __ATOMIC_RELEASE,
                               __HIP_MEMORY_SCOPE_AGENT);
        }
        int boff = 0;
        if (bid > 0) {
            int j = bid - 1;
            while (true) {
                int idx = j - t;
                unsigned long long s = (idx >= 0)
                    ? __hip_atomic_load(&st[idx], __ATOMIC_ACQUIRE,
                                        __HIP_MEMORY_SCOPE_AGENT)
                    : (2ull << 32);                       // virtual prefix 0
                int flag = (int)(s >> 32);
                unsigned long long pend = __ballot(flag == 0);
                unsigned long long pref = __ballot(flag == 2);
                int fp  = pref ? (__ffsll(pref) - 1) : 64;
                int fpd = pend ? (__ffsll(pend) - 1) : 64;
                if (fp < fpd) {
                    int val = (t <= fp) ? (int)(s & 0xffffffffu) : 0;
#pragma unroll
                    for (int off = 32; off >= 1; off >>= 1)
                        val += __shfl_xor(val, off);
                    boff += val;
                    break;
                } else if (fpd == 64) {                    // 64 aggregates
                    int val = (int)(s & 0xffffffffu);
#pragma unroll
                    for (int off = 32; off >= 1; off >>= 1)
                        val += __shfl_xor(val, off);
                    boff += val;
                    j -= 64;
                } else {
                    __builtin_amdgcn_s_sleep(2);           // pending: retry
                }
            }
            if (t == 0) {
                unsigned long long pub =
                    (2ull << 32) | (unsigned int)(boff + total);
                __hip_atomic_store(&st[bid], pub, __ATOMIC_RELEASE,
                                   __HIP_MEMORY_SCOPE_AGENT);
            }
        }
        if (t == 0) sh_boff = boff;
    }
    __syncthreads();
    if (i < BN) cursor[i] = sh_boff + excl;
}

// ---------------------------------------------------------------------------
// Kernel C: 4 edges/thread, coalesced loads, 4 independent atomic chains;
// single 4B scattered store per edge (src | mask-bit).
// ---------------------------------------------------------------------------
__global__ __launch_bounds__(256) void k_edge(
    const int* __restrict__ ei, const float* __restrict__ mask,
    int* __restrict__ cursor, int* __restrict__ esrc)
{
    int i = blockIdx.x * 256 + threadIdx.x;     // [0, BE/4)
    if (i >= BE / 4) return;
    int e0 = i * 4;
    int b  = e0 / EE;                            // EE%4==0 -> uniform batch
    int le = e0 - b * EE;
    const int* eb = ei + (size_t)b * 2 * EE;
    int4   sq = *(const int4*)(eb + le);
    int4   tq = *(const int4*)(eb + EE + le);
    float4 mq = *(const float4*)(mask + e0);
    int base = b * NN;

    int p0 = atomicAdd(&cursor[tq.x + base], 1);
    int p1 = atomicAdd(&cursor[tq.y + base], 1);
    int p2 = atomicAdd(&cursor[tq.z + base], 1);
    int p3 = atomicAdd(&cursor[tq.w + base], 1);
    esrc[p0] = (sq.x + base) | (mq.x > 0.f ? 0 : (int)0x80000000);
    esrc[p1] = (sq.y + base) | (mq.y > 0.f ? 0 : (int)0x80000000);
    esrc[p2] = (sq.z + base) | (mq.z > 0.f ? 0 : (int)0x80000000);
    esrc[p3] = (sq.w + base) | (mq.w > 0.f ? 0 : (int)0x80000000);
}

// ---------------------------------------------------------------------------
// Kernel D: one wave per target node, 8 edges/step + depth-2 prefetch of the
// next group's esrc/ssrc chain. Lane l owns exp for (edge l&7, head l>>3);
// __shfl distributes. Own-lane den + 3-shuffle reduce.  (R9 verbatim)
// ---------------------------------------------------------------------------
__global__ __launch_bounds__(256) void k_gather(
    const int* __restrict__ cursor, const int* __restrict__ esrc,
    const float* __restrict__ ssrc, const float* __restrict__ strg,
    const unsigned short* __restrict__ proj, const float* __restrict__ bias,
    float* __restrict__ out)
{
    int gid  = blockIdx.x * 256 + threadIdx.x;
    int node = gid >> 6;
    int lane = gid & 63;
    if (node >= BN) return;
    int h  = lane >> 3;
    int el = lane & 7;
    int hb = lane & 56;
    float st = strg[(size_t)node * HH + h];
    int lo = node ? cursor[node - 1] : 0;
    int hi = cursor[node];

    float acc0 = 0.f, acc1 = 0.f, acc2 = 0.f, acc3 = 0.f, deno = 0.f;

    // prologue: group 0's chain
    int  i0 = lo + el;
    bool v0 = i0 < hi;
    int  sv = v0 ? esrc[i0] : 0;
    int  s  = sv & 0x7fffffff;
    float f = ssrc[(size_t)s * HH + h];

    for (int p = lo; p < hi; p += 8) {
        int  i1 = p + 8 + el;
        bool v1 = i1 < hi;
        int  svn = v1 ? esrc[i1] : 0;
        float fn = ssrc[(size_t)(svn & 0x7fffffff) * HH + h];

        float c = f + st;
        c = c > 0.f ? c : 0.2f * c;                // leaky_relu(0.2)
        float ex = (v0 && sv >= 0) ? __expf(c) : 0.f;
        deno += ex;                                 // own-lane edge only

#pragma unroll
        for (int e = 0; e < 8; ++e) {
            float ee = __shfl(ex, e | hb);          // (edge e, this head)
            int   se = __shfl(s, e);
            ushort4 q = ((const ushort4*)(proj + (size_t)se * CC))[lane];
            acc0 += bf2f(q.x) * ee;
            acc1 += bf2f(q.y) * ee;
            acc2 += bf2f(q.z) * ee;
            acc3 += bf2f(q.w) * ee;
        }
        sv = svn; s = svn & 0x7fffffff; f = fn; v0 = v1;
    }

#pragma unroll
    for (int off = 1; off < 8; off <<= 1) deno += __shfl_xor(deno, off);

    float inv = 1.f / (deno + 1e-16f);
    float4 bv = ((const float4*)bias)[lane];
    float o0 = acc0 * inv + bv.x, o1 = acc1 * inv + bv.y;
    float o2 = acc2 * inv + bv.z, o3 = acc3 * inv + bv.w;
    o0 = o0 > 0.f ? o0 : __expf(o0) - 1.f;
    o1 = o1 > 0.f ? o1 : __expf(o1) - 1.f;
    o2 = o2 > 0.f ? o2 : __expf(o2) - 1.f;
    o3 = o3 > 0.f ? o3 : __expf(o3) - 1.f;
    ((float4*)(out + (size_t)node * CC))[lane] = make_float4(o0, o1, o2, o3);
}

// ---------------------------------------------------------------------------
extern "C" void kernel_launch(void* const* d_in, const int* in_sizes, int n_in,
                              void* d_out, int out_size, void* d_ws, size_t ws_size,
                              hipStream_t stream)
{
    const float* x     = (const float*)d_in[0];
    const int*   ei    = (const int*)  d_in[1];
    const float* mask  = (const float*)d_in[2];
    const float* Wm    = (const float*)d_in[3];
    const float* a_src = (const float*)d_in[4];
    const float* a_trg = (const float*)d_in[5];
    const float* bias  = (const float*)d_in[6];
    float* out = (float*)d_out;

    char* ws = (char*)d_ws;
    size_t off = 0;
    unsigned short* wb = (unsigned short*)(ws + off); off += (size_t)CC * FIN * 2; //  0.13 MB
    unsigned short* proj = (unsigned short*)(ws + off); off += (size_t)BN * CC * 2;// 20.48 MB
    float* ssrc = (float*)(ws + off); off += (size_t)BN * HH * 4;                  //  1.28 MB
    float* strg = (float*)(ws + off); off += (size_t)BN * HH * 4;                  //  1.28 MB
    int*   deg  = (int*)  (ws + off); off += (size_t)BN * 4;                       //  0.16 MB (8B-aligned end)
    unsigned long long* st = (unsigned long long*)(ws + off); off += 256 * 8;      //  look-back state
    int*   cursor = (int*)(ws + off); off += (size_t)BN * 4;                       //  0.16 MB
    int*   esrc   = (int*)(ws + off); off += (size_t)(BE + 64) * 4;                //  2.56 MB

    // one memset covers deg + st (contiguous)
    hipMemsetAsync(deg, 0, (size_t)BN * 4 + 256 * 8, stream);
    k_prep    <<<WCVT + CNTB, 256, 0, stream>>>(Wm, ei, wb, deg);
    k_gemm    <<<((BN + 127) / 128) * 2, 256, 0, stream>>>(x, wb, a_src, a_trg,
                                                           proj, ssrc, strg);
    k_scanfill<<<NB, 256, 0, stream>>>(deg, st, cursor);
    k_edge    <<<(BE / 4 + 255) / 256, 256, 0, stream>>>(ei, mask, cursor, esrc);
    k_gather  <<<(BN * 64) / 256, 256, 0, stream>>>(cursor, esrc, ssrc, strg,
                                                    proj, bias, out);
}

// Round 12
// 145.686 us; speedup vs baseline: 1.5743x; 1.0391x over previous
//
#include <hip/hip_runtime.h>
#include <hip/hip_bf16.h>

#define BB   4
#define NN   10000
#define EE   160000
#define FIN  256
#define HH   8
#define FO   32
#define CC   256            // H*FO
#define BN   40000          // B*N
#define BE   640000         // B*E
#define NB   157            // ceil(BN/256)
#define SCB  1250           // BN/32 score blocks

#define WCVT 32             // CC*FIN/8/256 blocks for W cvt
#define CNTB 625            // BE/4/256 blocks for histogram

typedef __attribute__((ext_vector_type(8))) __bf16 bf16x8;
typedef __attribute__((ext_vector_type(4))) float  f32x4;

__device__ __forceinline__ float bf2f(unsigned short u) {
    unsigned int v = ((unsigned int)u) << 16;
    return __uint_as_float(v);
}
__device__ __forceinline__ unsigned short f2bf(float f) {
    unsigned int u = __float_as_uint(f);
    u += 0x7fffu + ((u >> 16) & 1u);   // round-to-nearest-even
    return (unsigned short)(u >> 16);
}
// pack two f32 -> two bf16 (RNE) in one instruction
__device__ __forceinline__ unsigned int cvtpk(float lo, float hi) {
    unsigned int r;
    asm volatile("v_cvt_pk_bf16_f32 %0, %1, %2" : "=v"(r) : "v"(lo), "v"(hi));
    return r;
}

__device__ __forceinline__ void cvt8(const float* __restrict__ src,
                                     unsigned short* __restrict__ dst, int i)
{
    const float4* s = (const float4*)src + (size_t)i * 2;
    float4 v0 = s[0], v1 = s[1];
    float f[8] = {v0.x, v0.y, v0.z, v0.w, v1.x, v1.y, v1.z, v1.w};
    union { unsigned short u[8]; uint4 q; } o;
#pragma unroll
    for (int j = 0; j < 8; ++j) o.u[j] = f2bf(f[j]);
    ((uint4*)dst)[i] = o.q;
}

// 256-thread block exclusive scan (int). lds4 is a __shared__ int[4].
__device__ __forceinline__ int block_excl_scan_256(int v, int t, int* lds4,
                                                   int* total)
{
    int lane = t & 63, wid = t >> 6;
    int incl = v;
#pragma unroll
    for (int off = 1; off < 64; off <<= 1) {
        int u = __shfl_up(incl, off);
        if (lane >= off) incl += u;
    }
    if (lane == 63) lds4[wid] = incl;
    __syncthreads();
    int w0 = lds4[0], w1 = lds4[1], w2 = lds4[2], w3 = lds4[3];
    int woff = (wid > 0 ? w0 : 0) + (wid > 1 ? w1 : 0) + (wid > 2 ? w2 : 0);
    *total = w0 + w1 + w2 + w3;
    return woff + incl - v;
}

// ---------------------------------------------------------------------------
// Kernel P: W->bf16 cvt + deg histogram (4 edges/thread, int4).
// ---------------------------------------------------------------------------
__global__ __launch_bounds__(256) void k_prep(
    const float* __restrict__ Wm, const int* __restrict__ ei,
    unsigned short* __restrict__ wb, int* __restrict__ deg)
{
    int blk = blockIdx.x, t = threadIdx.x;
    if (blk < WCVT) {
        cvt8(Wm, wb, blk * 256 + t);
    } else {
        int i = (blk - WCVT) * 256 + t;             // 4 edges per thread
        int e0 = i * 4;
        int b  = e0 / EE;
        int le = e0 - b * EE;
        int4 tq = *(const int4*)(ei + (size_t)b * 2 * EE + EE + le);
        int base = b * NN;
        atomicAdd(&deg[tq.x + base], 1);
        atomicAdd(&deg[tq.y + base], 1);
        atomicAdd(&deg[tq.z + base], 1);
        atomicAdd(&deg[tq.w + base], 1);
    }
}

// ---------------------------------------------------------------------------
// Kernel 1: proj = x @ Wb^T via MFMA bf16 (128x128 tile, BK=64, 4 waves).
// R9 form: A staged from f32 x with cvt_pk + swizzled ds_write; B via
// global_load_lds from pre-swizzled source. No epilogue fusion.
// ---------------------------------------------------------------------------
__global__ __launch_bounds__(256) void k_gemm(
    const float* __restrict__ x, const unsigned short* __restrict__ wb,
    unsigned short* __restrict__ proj)
{
    __shared__ alignas(16) unsigned short As[128 * 64];
    __shared__ alignas(16) unsigned short Bs[128 * 64];

    const int t    = threadIdx.x;
    const int lane = t & 63;
    const int wid  = t >> 6;
    const int wr   = wid >> 1, wc = wid & 1;
    const int bm   = blockIdx.x >> 1;
    const int bn   = blockIdx.x & 1;
    const int row0 = bm * 128, col0 = bn * 128;

    const int srow = t >> 3;            // 0..31
    const int scol = (t & 7) * 8;

    f32x4 acc[4][4] = {};

    for (int kt = 0; kt < 4; ++kt) {
        const int k0 = kt * 64;
#pragma unroll
        for (int p = 0; p < 4; ++p) {
            int tr = p * 32 + srow;                       // tile row 0..127
            int swz = (tr & 7) << 3;
            int gra = row0 + tr; if (gra > BN - 1) gra = BN - 1;  // M-tail
            // A: f32 load + cvt_pk + swizzled LDS write
            const float4* xa = (const float4*)(x + (size_t)gra * FIN + k0 + scol);
            float4 v0 = xa[0], v1 = xa[1];
            uint4 w;
            w.x = cvtpk(v0.x, v0.y);
            w.y = cvtpk(v0.z, v0.w);
            w.z = cvtpk(v1.x, v1.y);
            w.w = cvtpk(v1.z, v1.w);
            *(uint4*)&As[tr * 64 + (scol ^ swz)] = w;
            // B: direct-to-LDS from pre-swizzled source
            const unsigned short* gb = wb + (size_t)(col0 + tr) * FIN + k0 + (scol ^ swz);
            __builtin_amdgcn_global_load_lds(
                (const __attribute__((address_space(1))) void*)gb,
                (__attribute__((address_space(3))) void*)&Bs[p * 2048 + t * 8],
                16, 0, 0);
        }
        __syncthreads();

#pragma unroll
        for (int kk = 0; kk < 2; ++kk) {
            bf16x8 af[4], bfr[4];
#pragma unroll
            for (int m = 0; m < 4; ++m) {
                int row = wr * 64 + m * 16 + (lane & 15);
                int col = (kk * 32 + (lane >> 4) * 8) ^ ((row & 7) << 3);
                af[m] = *(const bf16x8*)&As[row * 64 + col];
            }
#pragma unroll
            for (int n = 0; n < 4; ++n) {
                int row = wc * 64 + n * 16 + (lane & 15);
                int col = (kk * 32 + (lane >> 4) * 8) ^ ((row & 7) << 3);
                bfr[n] = *(const bf16x8*)&Bs[row * 64 + col];
            }
#pragma unroll
            for (int m = 0; m < 4; ++m)
#pragma unroll
                for (int n = 0; n < 4; ++n)
                    acc[m][n] = __builtin_amdgcn_mfma_f32_16x16x32_bf16(
                        af[m], bfr[n], acc[m][n], 0, 0, 0);
        }
        __syncthreads();
    }

    const int rbase = row0 + wr * 64 + (lane >> 4) * 4;
    const int cbase = col0 + wc * 64 + (lane & 15);
#pragma unroll
    for (int m = 0; m < 4; ++m)
#pragma unroll
        for (int n = 0; n < 4; ++n)
#pragma unroll
            for (int j = 0; j < 4; ++j) {
                int r = rbase + m * 16 + j;
                int c = cbase + n * 16;
                if (r < BN) proj[(size_t)r * CC + c] = f2bf(acc[m][n][j]);
            }
}

// ---------------------------------------------------------------------------
// Kernel S: combined grid. Blocks [0, NB): single-pass decoupled-lookback
// scan of deg -> cursor. Blocks [NB, NB+SCB): per-node scores from proj.
// The two halves are data-independent; scan blocks hold the low block ids
// (first dispatched, co-resident -> look-back cannot deadlock).
// ---------------------------------------------------------------------------
__global__ __launch_bounds__(256) void k_scanscore(
    const int* __restrict__ deg, unsigned long long* __restrict__ st,
    int* __restrict__ cursor, const unsigned short* __restrict__ proj,
    const float* __restrict__ a_src, const float* __restrict__ a_trg,
    float* __restrict__ ssrc, float* __restrict__ strg)
{
    const int t = threadIdx.x;

    if (blockIdx.x >= NB) {
        // ---- score path: node = sblk*32 + t>>3, head = t&7
        __shared__ float sa[CC], sb[CC];
        sa[t] = a_src[t];
        sb[t] = a_trg[t];
        __syncthreads();
        int sblk = blockIdx.x - NB;
        int node = sblk * 32 + (t >> 3);
        int h    = t & 7;
        const uint4* q4 = (const uint4*)(proj + (size_t)node * CC + h * 32);
        const float* pa = sa + h * 32;
        const float* pb = sb + h * 32;
        float vs = 0.f, vt = 0.f;
#pragma unroll
        for (int i = 0; i < 4; ++i) {
            uint4 q = q4[i];
            unsigned int v[4] = {q.x, q.y, q.z, q.w};
#pragma unroll
            for (int j = 0; j < 4; ++j) {
                float lo = __uint_as_float(v[j] << 16);
                float hi = __uint_as_float(v[j] & 0xffff0000u);
                int c = i * 8 + j * 2;
                vs += lo * pa[c] + hi * pa[c + 1];
                vt += lo * pb[c] + hi * pb[c + 1];
            }
        }
        ssrc[(size_t)node * HH + h] = vs;
        strg[(size_t)node * HH + h] = vt;
        return;
    }

    // ---- scan path (R11-validated decoupled look-back)
    __shared__ int w4b[4];
    __shared__ int sh_boff;
    const int bid = blockIdx.x;
    const int i = bid * 256 + t;
    int v = (i < BN) ? deg[i] : 0;

    int total;
    int excl = block_excl_scan_256(v, t, w4b, &total);

    if (t < 64) {
        if (t == 0) {
            unsigned long long pub =
                ((bid == 0 ? 2ull : 1ull) << 32) | (unsigned int)total;
            __hip_atomic_store(&st[bid], pub, __ATOMIC_RELEASE,
                               __HIP_MEMORY_SCOPE_AGENT);
        }
        int boff = 0;
        if (bid > 0) {
            int j = bid - 1;
            while (true) {
                int idx = j - t;
                unsigned long long s = (idx >= 0)
                    ? __hip_atomic_load(&st[idx], __ATOMIC_ACQUIRE,
                                        __HIP_MEMORY_SCOPE_AGENT)
                    : (2ull << 32);                       // virtual prefix 0
                int flag = (int)(s >> 32);
                unsigned long long pend = __ballot(flag == 0);
                unsigned long long pref = __ballot(flag == 2);
                int fp  = pref ? (__ffsll(pref) - 1) : 64;
                int fpd = pend ? (__ffsll(pend) - 1) : 64;
                if (fp < fpd) {
                    int val = (t <= fp) ? (int)(s & 0xffffffffu) : 0;
#pragma unroll
                    for (int off = 32; off >= 1; off >>= 1)
                        val += __shfl_xor(val, off);
                    boff += val;
                    break;
                } else if (fpd == 64) {                    // 64 aggregates
                    int val = (int)(s & 0xffffffffu);
#pragma unroll
                    for (int off = 32; off >= 1; off >>= 1)
                        val += __shfl_xor(val, off);
                    boff += val;
                    j -= 64;
                } else {
                    __builtin_amdgcn_s_sleep(2);           // pending: retry
                }
            }
            if (t == 0) {
                unsigned long long pub =
                    (2ull << 32) | (unsigned int)(boff + total);
                __hip_atomic_store(&st[bid], pub, __ATOMIC_RELEASE,
                                   __HIP_MEMORY_SCOPE_AGENT);
            }
        }
        if (t == 0) sh_boff = boff;
    }
    __syncthreads();
    if (i < BN) cursor[i] = sh_boff + excl;
}

// ---------------------------------------------------------------------------
// Kernel C: 4 edges/thread, coalesced loads, 4 independent atomic chains;
// single 4B scattered store per edge (src | mask-bit).
// ---------------------------------------------------------------------------
__global__ __launch_bounds__(256) void k_edge(
    const int* __restrict__ ei, const float* __restrict__ mask,
    int* __restrict__ cursor, int* __restrict__ esrc)
{
    int i = blockIdx.x * 256 + threadIdx.x;     // [0, BE/4)
    if (i >= BE / 4) return;
    int e0 = i * 4;
    int b  = e0 / EE;                            // EE%4==0 -> uniform batch
    int le = e0 - b * EE;
    const int* eb = ei + (size_t)b * 2 * EE;
    int4   sq = *(const int4*)(eb + le);
    int4   tq = *(const int4*)(eb + EE + le);
    float4 mq = *(const float4*)(mask + e0);
    int base = b * NN;

    int p0 = atomicAdd(&cursor[tq.x + base], 1);
    int p1 = atomicAdd(&cursor[tq.y + base], 1);
    int p2 = atomicAdd(&cursor[tq.z + base], 1);
    int p3 = atomicAdd(&cursor[tq.w + base], 1);
    esrc[p0] = (sq.x + base) | (mq.x > 0.f ? 0 : (int)0x80000000);
    esrc[p1] = (sq.y + base) | (mq.y > 0.f ? 0 : (int)0x80000000);
    esrc[p2] = (sq.z + base) | (mq.z > 0.f ? 0 : (int)0x80000000);
    esrc[p3] = (sq.w + base) | (mq.w > 0.f ? 0 : (int)0x80000000);
}

// ---------------------------------------------------------------------------
// Kernel D: one wave per target node, 8 edges/step + depth-2 prefetch of the
// next group's esrc/ssrc chain. Lane l owns exp for (edge l&7, head l>>3);
// __shfl distributes. Own-lane den + 3-shuffle reduce.  (R9 verbatim)
// ---------------------------------------------------------------------------
__global__ __launch_bounds__(256) void k_gather(
    const int* __restrict__ cursor, const int* __restrict__ esrc,
    const float* __restrict__ ssrc, const float* __restrict__ strg,
    const unsigned short* __restrict__ proj, const float* __restrict__ bias,
    float* __restrict__ out)
{
    int gid  = blockIdx.x * 256 + threadIdx.x;
    int node = gid >> 6;
    int lane = gid & 63;
    if (node >= BN) return;
    int h  = lane >> 3;
    int el = lane & 7;
    int hb = lane & 56;
    float st = strg[(size_t)node * HH + h];
    int lo = node ? cursor[node - 1] : 0;
    int hi = cursor[node];

    float acc0 = 0.f, acc1 = 0.f, acc2 = 0.f, acc3 = 0.f, deno = 0.f;

    // prologue: group 0's chain
    int  i0 = lo + el;
    bool v0 = i0 < hi;
    int  sv = v0 ? esrc[i0] : 0;
    int  s  = sv & 0x7fffffff;
    float f = ssrc[(size_t)s * HH + h];

    for (int p = lo; p < hi; p += 8) {
        int  i1 = p + 8 + el;
        bool v1 = i1 < hi;
        int  svn = v1 ? esrc[i1] : 0;
        float fn = ssrc[(size_t)(svn & 0x7fffffff) * HH + h];

        float c = f + st;
        c = c > 0.f ? c : 0.2f * c;                // leaky_relu(0.2)
        float ex = (v0 && sv >= 0) ? __expf(c) : 0.f;
        deno += ex;                                 // own-lane edge only

#pragma unroll
        for (int e = 0; e < 8; ++e) {
            float ee = __shfl(ex, e | hb);          // (edge e, this head)
            int   se = __shfl(s, e);
            ushort4 q = ((const ushort4*)(proj + (size_t)se * CC))[lane];
            acc0 += bf2f(q.x) * ee;
            acc1 += bf2f(q.y) * ee;
            acc2 += bf2f(q.z) * ee;
            acc3 += bf2f(q.w) * ee;
        }
        sv = svn; s = svn & 0x7fffffff; f = fn; v0 = v1;
    }

#pragma unroll
    for (int off = 1; off < 8; off <<= 1) deno += __shfl_xor(deno, off);

    float inv = 1.f / (deno + 1e-16f);
    float4 bv = ((const float4*)bias)[lane];
    float o0 = acc0 * inv + bv.x, o1 = acc1 * inv + bv.y;
    float o2 = acc2 * inv + bv.z, o3 = acc3 * inv + bv.w;
    o0 = o0 > 0.f ? o0 : __expf(o0) - 1.f;
    o1 = o1 > 0.f ? o1 : __expf(o1) - 1.f;
    o2 = o2 > 0.f ? o2 : __expf(o2) - 1.f;
    o3 = o3 > 0.f ? o3 : __expf(o3) - 1.f;
    ((float4*)(out + (size_t)node * CC))[lane] = make_float4(o0, o1, o2, o3);
}

// ---------------------------------------------------------------------------
extern "C" void kernel_launch(void* const* d_in, const int* in_sizes, int n_in,
                              void* d_out, int out_size, void* d_ws, size_t ws_size,
                              hipStream_t stream)
{
    const float* x     = (const float*)d_in[0];
    const int*   ei    = (const int*)  d_in[1];
    const float* mask  = (const float*)d_in[2];
    const float* Wm    = (const float*)d_in[3];
    const float* a_src = (const float*)d_in[4];
    const float* a_trg = (const float*)d_in[5];
    const float* bias  = (const float*)d_in[6];
    float* out = (float*)d_out;

    char* ws = (char*)d_ws;
    size_t off = 0;
    unsigned short* wb = (unsigned short*)(ws + off); off += (size_t)CC * FIN * 2; //  0.13 MB
    unsigned short* proj = (unsigned short*)(ws + off); off += (size_t)BN * CC * 2;// 20.48 MB
    float* ssrc = (float*)(ws + off); off += (size_t)BN * HH * 4;                  //  1.28 MB
    float* strg = (float*)(ws + off); off += (size_t)BN * HH * 4;                  //  1.28 MB
    int*   deg  = (int*)  (ws + off); off += (size_t)BN * 4;                       //  0.16 MB
    unsigned long long* st = (unsigned long long*)(ws + off); off += 256 * 8;      //  look-back state
    int*   cursor = (int*)(ws + off); off += (size_t)BN * 4;                       //  0.16 MB
    int*   esrc   = (int*)(ws + off); off += (size_t)(BE + 64) * 4;                //  2.56 MB

    // one memset covers deg + st (contiguous)
    hipMemsetAsync(deg, 0, (size_t)BN * 4 + 256 * 8, stream);
    k_prep     <<<WCVT + CNTB, 256, 0, stream>>>(Wm, ei, wb, deg);
    k_gemm     <<<((BN + 127) / 128) * 2, 256, 0, stream>>>(x, wb, proj);
    k_scanscore<<<NB + SCB, 256, 0, stream>>>(deg, st, cursor, proj,
                                              a_src, a_trg, ssrc, strg);
    k_edge     <<<(BE / 4 + 255) / 256, 256, 0, stream>>>(ei, mask, cursor, esrc);
    k_gather   <<<(BN * 64) / 256, 256, 0, stream>>>(cursor, esrc, ssrc, strg,
                                                     proj, bias, out);
}

// Round 13
// 137.345 us; speedup vs baseline: 1.6699x; 1.0607x over previous
//
#include <hip/hip_runtime.h>
#include <hip/hip_bf16.h>

#define BB   4
#define NN   10000
#define EE   160000
#define FIN  256
#define HH   8
#define FO   32
#define CC   256            // H*FO
#define BN   40000          // B*N
#define BE   640000         // B*E
#define NB   157            // ceil(BN/256) scan blocks
#define SCB  1250           // BN/32 score blocks
#define GMB  313            // ceil(BN/128) gemm blocks
#define HSB  313            // ceil(BE/4/512) histogram blocks

typedef __attribute__((ext_vector_type(8))) __bf16 bf16x8;
typedef __attribute__((ext_vector_type(4))) float  f32x4;

__device__ __forceinline__ float bf2f(unsigned short u) {
    unsigned int v = ((unsigned int)u) << 16;
    return __uint_as_float(v);
}
__device__ __forceinline__ unsigned short f2bf(float f) {
    unsigned int u = __float_as_uint(f);
    u += 0x7fffu + ((u >> 16) & 1u);   // round-to-nearest-even
    return (unsigned short)(u >> 16);
}
// pack two f32 -> two bf16 (RNE) in one instruction
__device__ __forceinline__ unsigned int cvtpk(float lo, float hi) {
    unsigned int r;
    asm volatile("v_cvt_pk_bf16_f32 %0, %1, %2" : "=v"(r) : "v"(lo), "v"(hi));
    return r;
}

// 256-thread block exclusive scan (int). lds4 is a __shared__ int[4].
__device__ __forceinline__ int block_excl_scan_256(int v, int t, int* lds4,
                                                   int* total)
{
    int lane = t & 63, wid = t >> 6;
    int incl = v;
#pragma unroll
    for (int off = 1; off < 64; off <<= 1) {
        int u = __shfl_up(incl, off);
        if (lane >= off) incl += u;
    }
    if (lane == 63) lds4[wid] = incl;
    __syncthreads();
    int w0 = lds4[0], w1 = lds4[1], w2 = lds4[2], w3 = lds4[3];
    int woff = (wid > 0 ? w0 : 0) + (wid > 1 ? w1 : 0) + (wid > 2 ? w2 : 0);
    *total = w0 + w1 + w2 + w3;
    return woff + incl - v;
}

// ---------------------------------------------------------------------------
// Kernel G: combined grid, 512 threads.
//   blocks [0, GMB):      proj = x @ W^T, 128x256 tile (full N), 8 waves 2x4.
//                         A and B both reg-staged from f32 with cvt_pk and
//                         both-sides XOR-swizzled LDS.  x is read ONCE.
//   blocks [GMB, +HSB):   deg histogram, 4 edges/thread (int4).
// ---------------------------------------------------------------------------
__global__ __launch_bounds__(512) void k_gemmhist(
    const float* __restrict__ x, const float* __restrict__ Wm,
    const int* __restrict__ ei, unsigned short* __restrict__ proj,
    int* __restrict__ deg)
{
    __shared__ alignas(16) unsigned short As[128 * 64];   // 16 KB
    __shared__ alignas(16) unsigned short Bs[256 * 64];   // 32 KB

    const int t = threadIdx.x;

    if (blockIdx.x >= GMB) {
        // ---- histogram path
        int i = (blockIdx.x - GMB) * 512 + t;     // [0, BE/4)
        if (i < BE / 4) {
            int e0 = i * 4;
            int b  = e0 / EE;                     // EE%4==0 -> uniform batch
            int le = e0 - b * EE;
            int4 tq = *(const int4*)(ei + (size_t)b * 2 * EE + EE + le);
            int base = b * NN;
            atomicAdd(&deg[tq.x + base], 1);
            atomicAdd(&deg[tq.y + base], 1);
            atomicAdd(&deg[tq.z + base], 1);
            atomicAdd(&deg[tq.w + base], 1);
        }
        return;
    }

    // ---- gemm path
    const int lane = t & 63;
    const int wid  = t >> 6;                      // 0..7
    const int wr   = wid >> 2, wc = wid & 3;      // 2 x 4 wave grid
    const int row0 = blockIdx.x * 128;

    const int srow = t >> 3;                      // 0..63
    const int scol = (t & 7) * 8;                 // 0..56

    f32x4 acc[4][4] = {};

    for (int kt = 0; kt < 4; ++kt) {
        const int k0 = kt * 64;
        // stage A: 128x64 bf16 from f32 x (2 passes)
#pragma unroll
        for (int p = 0; p < 2; ++p) {
            int tr  = p * 64 + srow;
            int swz = (tr & 7) << 3;
            int gra = row0 + tr; if (gra > BN - 1) gra = BN - 1;  // M-tail
            const float4* xa = (const float4*)(x + (size_t)gra * FIN + k0 + scol);
            float4 v0 = xa[0], v1 = xa[1];
            uint4 w;
            w.x = cvtpk(v0.x, v0.y);
            w.y = cvtpk(v0.z, v0.w);
            w.z = cvtpk(v1.x, v1.y);
            w.w = cvtpk(v1.z, v1.w);
            *(uint4*)&As[tr * 64 + (scol ^ swz)] = w;
        }
        // stage B: 256x64 bf16 from f32 Wm (4 passes)
#pragma unroll
        for (int p = 0; p < 4; ++p) {
            int tr  = p * 64 + srow;                          // output col
            int swz = (tr & 7) << 3;
            const float4* wa = (const float4*)(Wm + (size_t)tr * FIN + k0 + scol);
            float4 v0 = wa[0], v1 = wa[1];
            uint4 w;
            w.x = cvtpk(v0.x, v0.y);
            w.y = cvtpk(v0.z, v0.w);
            w.z = cvtpk(v1.x, v1.y);
            w.w = cvtpk(v1.z, v1.w);
            *(uint4*)&Bs[tr * 64 + (scol ^ swz)] = w;
        }
        __syncthreads();

#pragma unroll
        for (int kk = 0; kk < 2; ++kk) {
            bf16x8 af[4], bfr[4];
#pragma unroll
            for (int m = 0; m < 4; ++m) {
                int row = wr * 64 + m * 16 + (lane & 15);
                int col = (kk * 32 + (lane >> 4) * 8) ^ ((row & 7) << 3);
                af[m] = *(const bf16x8*)&As[row * 64 + col];
            }
#pragma unroll
            for (int n = 0; n < 4; ++n) {
                int row = wc * 64 + n * 16 + (lane & 15);
                int col = (kk * 32 + (lane >> 4) * 8) ^ ((row & 7) << 3);
                bfr[n] = *(const bf16x8*)&Bs[row * 64 + col];
            }
#pragma unroll
            for (int m = 0; m < 4; ++m)
#pragma unroll
                for (int n = 0; n < 4; ++n)
                    acc[m][n] = __builtin_amdgcn_mfma_f32_16x16x32_bf16(
                        af[m], bfr[n], acc[m][n], 0, 0, 0);
        }
        __syncthreads();
    }

    const int rbase = row0 + wr * 64 + (lane >> 4) * 4;
    const int cbase = wc * 64 + (lane & 15);
#pragma unroll
    for (int m = 0; m < 4; ++m)
#pragma unroll
        for (int n = 0; n < 4; ++n)
#pragma unroll
            for (int j = 0; j < 4; ++j) {
                int r = rbase + m * 16 + j;
                int c = cbase + n * 16;
                if (r < BN) proj[(size_t)r * CC + c] = f2bf(acc[m][n][j]);
            }
}

// ---------------------------------------------------------------------------
// Kernel S: combined grid. Blocks [0, NB): single-pass decoupled-lookback
// scan of deg -> cursor. Blocks [NB, NB+SCB): per-node scores from proj.
// ---------------------------------------------------------------------------
__global__ __launch_bounds__(256) void k_scanscore(
    const int* __restrict__ deg, unsigned long long* __restrict__ st,
    int* __restrict__ cursor, const unsigned short* __restrict__ proj,
    const float* __restrict__ a_src, const float* __restrict__ a_trg,
    float* __restrict__ ssrc, float* __restrict__ strg)
{
    const int t = threadIdx.x;

    if (blockIdx.x >= NB) {
        // ---- score path: node = sblk*32 + t>>3, head = t&7
        __shared__ float sa[CC], sb[CC];
        sa[t] = a_src[t];
        sb[t] = a_trg[t];
        __syncthreads();
        int sblk = blockIdx.x - NB;
        int node = sblk * 32 + (t >> 3);
        int h    = t & 7;
        const uint4* q4 = (const uint4*)(proj + (size_t)node * CC + h * 32);
        const float* pa = sa + h * 32;
        const float* pb = sb + h * 32;
        float vs = 0.f, vt = 0.f;
#pragma unroll
        for (int i = 0; i < 4; ++i) {
            uint4 q = q4[i];
            unsigned int v[4] = {q.x, q.y, q.z, q.w};
#pragma unroll
            for (int j = 0; j < 4; ++j) {
                float lo = __uint_as_float(v[j] << 16);
                float hi = __uint_as_float(v[j] & 0xffff0000u);
                int c = i * 8 + j * 2;
                vs += lo * pa[c] + hi * pa[c + 1];
                vt += lo * pb[c] + hi * pb[c + 1];
            }
        }
        ssrc[(size_t)node * HH + h] = vs;
        strg[(size_t)node * HH + h] = vt;
        return;
    }

    // ---- scan path (decoupled look-back, validated R11/R12)
    __shared__ int w4b[4];
    __shared__ int sh_boff;
    const int bid = blockIdx.x;
    const int i = bid * 256 + t;
    int v = (i < BN) ? deg[i] : 0;

    int total;
    int excl = block_excl_scan_256(v, t, w4b, &total);

    if (t < 64) {
        if (t == 0) {
            unsigned long long pub =
                ((bid == 0 ? 2ull : 1ull) << 32) | (unsigned int)total;
            __hip_atomic_store(&st[bid], pub, __ATOMIC_RELEASE,
                               __HIP_MEMORY_SCOPE_AGENT);
        }
        int boff = 0;
        if (bid > 0) {
            int j = bid - 1;
            while (true) {
                int idx = j - t;
                unsigned long long s = (idx >= 0)
                    ? __hip_atomic_load(&st[idx], __ATOMIC_ACQUIRE,
                                        __HIP_MEMORY_SCOPE_AGENT)
                    : (2ull << 32);                       // virtual prefix 0
                int flag = (int)(s >> 32);
                unsigned long long pend = __ballot(flag == 0);
                unsigned long long pref = __ballot(flag == 2);
                int fp  = pref ? (__ffsll(pref) - 1) : 64;
                int fpd = pend ? (__ffsll(pend) - 1) : 64;
                if (fp < fpd) {
                    int val = (t <= fp) ? (int)(s & 0xffffffffu) : 0;
#pragma unroll
                    for (int off = 32; off >= 1; off >>= 1)
                        val += __shfl_xor(val, off);
                    boff += val;
                    break;
                } else if (fpd == 64) {                    // 64 aggregates
                    int val = (int)(s & 0xffffffffu);
#pragma unroll
                    for (int off = 32; off >= 1; off >>= 1)
                        val += __shfl_xor(val, off);
                    boff += val;
                    j -= 64;
                } else {
                    __builtin_amdgcn_s_sleep(2);           // pending: retry
                }
            }
            if (t == 0) {
                unsigned long long pub =
                    (2ull << 32) | (unsigned int)(boff + total);
                __hip_atomic_store(&st[bid], pub, __ATOMIC_RELEASE,
                                   __HIP_MEMORY_SCOPE_AGENT);
            }
        }
        if (t == 0) sh_boff = boff;
    }
    __syncthreads();
    if (i < BN) cursor[i] = sh_boff + excl;
}

// ---------------------------------------------------------------------------
// Kernel C: 4 edges/thread, coalesced loads, 4 independent atomic chains;
// single 4B scattered store per edge (src | mask-bit).
// ---------------------------------------------------------------------------
__global__ __launch_bounds__(256) void k_edge(
    const int* __restrict__ ei, const float* __restrict__ mask,
    int* __restrict__ cursor, int* __restrict__ esrc)
{
    int i = blockIdx.x * 256 + threadIdx.x;     // [0, BE/4)
    if (i >= BE / 4) return;
    int e0 = i * 4;
    int b  = e0 / EE;                            // EE%4==0 -> uniform batch
    int le = e0 - b * EE;
    const int* eb = ei + (size_t)b * 2 * EE;
    int4   sq = *(const int4*)(eb + le);
    int4   tq = *(const int4*)(eb + EE + le);
    float4 mq = *(const float4*)(mask + e0);
    int base = b * NN;

    int p0 = atomicAdd(&cursor[tq.x + base], 1);
    int p1 = atomicAdd(&cursor[tq.y + base], 1);
    int p2 = atomicAdd(&cursor[tq.z + base], 1);
    int p3 = atomicAdd(&cursor[tq.w + base], 1);
    esrc[p0] = (sq.x + base) | (mq.x > 0.f ? 0 : (int)0x80000000);
    esrc[p1] = (sq.y + base) | (mq.y > 0.f ? 0 : (int)0x80000000);
    esrc[p2] = (sq.z + base) | (mq.z > 0.f ? 0 : (int)0x80000000);
    esrc[p3] = (sq.w + base) | (mq.w > 0.f ? 0 : (int)0x80000000);
}

// ---------------------------------------------------------------------------
// Kernel D: one wave per target node, 8 edges/step + depth-2 prefetch of the
// next group's esrc/ssrc chain. Lane l owns exp for (edge l&7, head l>>3);
// __shfl distributes. Own-lane den + 3-shuffle reduce.
// ---------------------------------------------------------------------------
__global__ __launch_bounds__(256) void k_gather(
    const int* __restrict__ cursor, const int* __restrict__ esrc,
    const float* __restrict__ ssrc, const float* __restrict__ strg,
    const unsigned short* __restrict__ proj, const float* __restrict__ bias,
    float* __restrict__ out)
{
    int gid  = blockIdx.x * 256 + threadIdx.x;
    int node = gid >> 6;
    int lane = gid & 63;
    if (node >= BN) return;
    int h  = lane >> 3;
    int el = lane & 7;
    int hb = lane & 56;
    float st = strg[(size_t)node * HH + h];
    int lo = node ? cursor[node - 1] : 0;
    int hi = cursor[node];

    const char* projc = (const char*)proj;
    const unsigned lb = lane * 8u;               // lane byte offset in row

    float acc0 = 0.f, acc1 = 0.f, acc2 = 0.f, acc3 = 0.f, deno = 0.f;

    // prologue: group 0's chain
    int  i0 = lo + el;
    bool v0 = i0 < hi;
    int  sv = v0 ? esrc[i0] : 0;
    int  s  = sv & 0x7fffffff;
    float f = ssrc[(size_t)s * HH + h];

    for (int p = lo; p < hi; p += 8) {
        int  i1 = p + 8 + el;
        bool v1 = i1 < hi;
        int  svn = v1 ? esrc[i1] : 0;
        float fn = ssrc[(size_t)(svn & 0x7fffffff) * HH + h];

        float c = f + st;
        c = c > 0.f ? c : 0.2f * c;                // leaky_relu(0.2)
        float ex = (v0 && sv >= 0) ? __expf(c) : 0.f;
        deno += ex;                                 // own-lane edge only

#pragma unroll
        for (int e = 0; e < 8; ++e) {
            float ee = __shfl(ex, e | hb);          // (edge e, this head)
            int   se = __shfl(s, e);
            ushort4 q = *(const ushort4*)(projc + (((unsigned)se << 9) + lb));
            acc0 += bf2f(q.x) * ee;
            acc1 += bf2f(q.y) * ee;
            acc2 += bf2f(q.z) * ee;
            acc3 += bf2f(q.w) * ee;
        }
        sv = svn; s = svn & 0x7fffffff; f = fn; v0 = v1;
    }

#pragma unroll
    for (int off = 1; off < 8; off <<= 1) deno += __shfl_xor(deno, off);

    float inv = 1.f / (deno + 1e-16f);
    float4 bv = ((const float4*)bias)[lane];
    float o0 = acc0 * inv + bv.x, o1 = acc1 * inv + bv.y;
    float o2 = acc2 * inv + bv.z, o3 = acc3 * inv + bv.w;
    o0 = o0 > 0.f ? o0 : __expf(o0) - 1.f;
    o1 = o1 > 0.f ? o1 : __expf(o1) - 1.f;
    o2 = o2 > 0.f ? o2 : __expf(o2) - 1.f;
    o3 = o3 > 0.f ? o3 : __expf(o3) - 1.f;
    ((float4*)(out + (size_t)node * CC))[lane] = make_float4(o0, o1, o2, o3);
}

// ---------------------------------------------------------------------------
extern "C" void kernel_launch(void* const* d_in, const int* in_sizes, int n_in,
                              void* d_out, int out_size, void* d_ws, size_t ws_size,
                              hipStream_t stream)
{
    const float* x     = (const float*)d_in[0];
    const int*   ei    = (const int*)  d_in[1];
    const float* mask  = (const float*)d_in[2];
    const float* Wm    = (const float*)d_in[3];
    const float* a_src = (const float*)d_in[4];
    const float* a_trg = (const float*)d_in[5];
    const float* bias  = (const float*)d_in[6];
    float* out = (float*)d_out;

    char* ws = (char*)d_ws;
    size_t off = 0;
    unsigned short* proj = (unsigned short*)(ws + off); off += (size_t)BN * CC * 2;// 20.48 MB
    float* ssrc = (float*)(ws + off); off += (size_t)BN * HH * 4;                  //  1.28 MB
    float* strg = (float*)(ws + off); off += (size_t)BN * HH * 4;                  //  1.28 MB
    int*   deg  = (int*)  (ws + off); off += (size_t)BN * 4;                       //  0.16 MB
    unsigned long long* st = (unsigned long long*)(ws + off); off += 256 * 8;      //  look-back state
    int*   cursor = (int*)(ws + off); off += (size_t)BN * 4;                       //  0.16 MB
    int*   esrc   = (int*)(ws + off); off += (size_t)(BE + 64) * 4;                //  2.56 MB

    // one memset covers deg + st (contiguous)
    hipMemsetAsync(deg, 0, (size_t)BN * 4 + 256 * 8, stream);
    k_gemmhist <<<GMB + HSB, 512, 0, stream>>>(x, Wm, ei, proj, deg);
    k_scanscore<<<NB + SCB, 256, 0, stream>>>(deg, st, cursor, proj,
                                              a_src, a_trg, ssrc, strg);
    k_edge     <<<(BE / 4 + 255) / 256, 256, 0, stream>>>(ei, mask, cursor, esrc);
    k_gather   <<<(BN * 64) / 256, 256, 0, stream>>>(cursor, esrc, ssrc, strg,
                                                     proj, bias, out);
}

// Round 14
// 137.218 us; speedup vs baseline: 1.6714x; 1.0009x over previous
//
#include <hip/hip_runtime.h>
#include <hip/hip_bf16.h>

#define BB   4
#define NN   10000
#define EE   160000
#define FIN  256
#define HH   8
#define FO   32
#define CC   256            // H*FO
#define BN   40000          // B*N
#define BE   640000         // B*E
#define NB   157            // ceil(BN/256) scan blocks
#define SCB  1250           // BN/32 score blocks
#define GMB  313            // ceil(BN/128) gemm blocks
#define HSB  313            // ceil(BE/4/512) histogram blocks

typedef __attribute__((ext_vector_type(8))) __bf16 bf16x8;
typedef __attribute__((ext_vector_type(4))) float  f32x4;

__device__ __forceinline__ float bf2f(unsigned short u) {
    unsigned int v = ((unsigned int)u) << 16;
    return __uint_as_float(v);
}
__device__ __forceinline__ unsigned short f2bf(float f) {
    unsigned int u = __float_as_uint(f);
    u += 0x7fffu + ((u >> 16) & 1u);   // round-to-nearest-even
    return (unsigned short)(u >> 16);
}
// pack two f32 -> two bf16 (RNE) in one instruction
__device__ __forceinline__ unsigned int cvtpk(float lo, float hi) {
    unsigned int r;
    asm volatile("v_cvt_pk_bf16_f32 %0, %1, %2" : "=v"(r) : "v"(lo), "v"(hi));
    return r;
}

// 256-thread block exclusive scan (int). lds4 is a __shared__ int[4].
__device__ __forceinline__ int block_excl_scan_256(int v, int t, int* lds4,
                                                   int* total)
{
    int lane = t & 63, wid = t >> 6;
    int incl = v;
#pragma unroll
    for (int off = 1; off < 64; off <<= 1) {
        int u = __shfl_up(incl, off);
        if (lane >= off) incl += u;
    }
    if (lane == 63) lds4[wid] = incl;
    __syncthreads();
    int w0 = lds4[0], w1 = lds4[1], w2 = lds4[2], w3 = lds4[3];
    int woff = (wid > 0 ? w0 : 0) + (wid > 1 ? w1 : 0) + (wid > 2 ? w2 : 0);
    *total = w0 + w1 + w2 + w3;
    return woff + incl - v;
}

// ---------------------------------------------------------------------------
// Kernel G: combined grid, 512 threads.
//   blocks [0, GMB):    proj = x @ W^T, 128x256 tile, 8 waves 2x4, BK=64.
//                       T14 pipeline: kt+1's f32 tiles prefetched into regs
//                       during kt's MFMAs; cvt_pk + both-sides-swizzled LDS.
//   blocks [GMB,+HSB):  deg histogram, 4 edges/thread (int4).
// ---------------------------------------------------------------------------
__global__ __launch_bounds__(512) void k_gemmhist(
    const float* __restrict__ x, const float* __restrict__ Wm,
    const int* __restrict__ ei, unsigned short* __restrict__ proj,
    int* __restrict__ deg)
{
    __shared__ alignas(16) unsigned short As[128 * 64];   // 16 KB
    __shared__ alignas(16) unsigned short Bs[256 * 64];   // 32 KB

    const int t = threadIdx.x;

    if (blockIdx.x >= GMB) {
        // ---- histogram path
        int i = (blockIdx.x - GMB) * 512 + t;     // [0, BE/4)
        if (i < BE / 4) {
            int e0 = i * 4;
            int b  = e0 / EE;                     // EE%4==0 -> uniform batch
            int le = e0 - b * EE;
            int4 tq = *(const int4*)(ei + (size_t)b * 2 * EE + EE + le);
            int base = b * NN;
            atomicAdd(&deg[tq.x + base], 1);
            atomicAdd(&deg[tq.y + base], 1);
            atomicAdd(&deg[tq.z + base], 1);
            atomicAdd(&deg[tq.w + base], 1);
        }
        return;
    }

    // ---- gemm path
    const int lane = t & 63;
    const int wid  = t >> 6;                      // 0..7
    const int wr   = wid >> 2, wc = wid & 3;      // 2 x 4 wave grid
    const int row0 = blockIdx.x * 128;

    const int srow = t >> 3;                      // 0..63
    const int scol = (t & 7) * 8;                 // 0..56

    // staging addresses (row part is kt-invariant)
    const float* xbase[2];
#pragma unroll
    for (int p = 0; p < 2; ++p) {
        int gra = row0 + p * 64 + srow;
        if (gra > BN - 1) gra = BN - 1;           // M-tail clamp
        xbase[p] = x + (size_t)gra * FIN + scol;
    }
    const float* wbase[4];
#pragma unroll
    for (int p = 0; p < 4; ++p)
        wbase[p] = Wm + (size_t)(p * 64 + srow) * FIN + scol;

    float4 ra[2][2], rb[4][2];
    // prologue: load kt=0 tiles into regs
#pragma unroll
    for (int p = 0; p < 2; ++p) {
        ra[p][0] = ((const float4*)xbase[p])[0];
        ra[p][1] = ((const float4*)xbase[p])[1];
    }
#pragma unroll
    for (int p = 0; p < 4; ++p) {
        rb[p][0] = ((const float4*)wbase[p])[0];
        rb[p][1] = ((const float4*)wbase[p])[1];
    }

    f32x4 acc[4][4] = {};

    for (int kt = 0; kt < 4; ++kt) {
        // ---- cvt + swizzled ds_write of current tiles from regs
#pragma unroll
        for (int p = 0; p < 2; ++p) {
            int tr  = p * 64 + srow;
            int swz = (tr & 7) << 3;
            uint4 w;
            w.x = cvtpk(ra[p][0].x, ra[p][0].y);
            w.y = cvtpk(ra[p][0].z, ra[p][0].w);
            w.z = cvtpk(ra[p][1].x, ra[p][1].y);
            w.w = cvtpk(ra[p][1].z, ra[p][1].w);
            *(uint4*)&As[tr * 64 + (scol ^ swz)] = w;
        }
#pragma unroll
        for (int p = 0; p < 4; ++p) {
            int tr  = p * 64 + srow;
            int swz = (tr & 7) << 3;
            uint4 w;
            w.x = cvtpk(rb[p][0].x, rb[p][0].y);
            w.y = cvtpk(rb[p][0].z, rb[p][0].w);
            w.z = cvtpk(rb[p][1].x, rb[p][1].y);
            w.w = cvtpk(rb[p][1].z, rb[p][1].w);
            *(uint4*)&Bs[tr * 64 + (scol ^ swz)] = w;
        }
        __syncthreads();

        // ---- issue next K-step's loads (overlap with MFMA below)
        if (kt < 3) {
            const int k1 = (kt + 1) * 64;
#pragma unroll
            for (int p = 0; p < 2; ++p) {
                ra[p][0] = ((const float4*)(xbase[p] + k1))[0];
                ra[p][1] = ((const float4*)(xbase[p] + k1))[1];
            }
#pragma unroll
            for (int p = 0; p < 4; ++p) {
                rb[p][0] = ((const float4*)(wbase[p] + k1))[0];
                rb[p][1] = ((const float4*)(wbase[p] + k1))[1];
            }
        }

        // ---- MFMA from LDS
#pragma unroll
        for (int kk = 0; kk < 2; ++kk) {
            bf16x8 af[4], bfr[4];
#pragma unroll
            for (int m = 0; m < 4; ++m) {
                int row = wr * 64 + m * 16 + (lane & 15);
                int col = (kk * 32 + (lane >> 4) * 8) ^ ((row & 7) << 3);
                af[m] = *(const bf16x8*)&As[row * 64 + col];
            }
#pragma unroll
            for (int n = 0; n < 4; ++n) {
                int row = wc * 64 + n * 16 + (lane & 15);
                int col = (kk * 32 + (lane >> 4) * 8) ^ ((row & 7) << 3);
                bfr[n] = *(const bf16x8*)&Bs[row * 64 + col];
            }
#pragma unroll
            for (int m = 0; m < 4; ++m)
#pragma unroll
                for (int n = 0; n < 4; ++n)
                    acc[m][n] = __builtin_amdgcn_mfma_f32_16x16x32_bf16(
                        af[m], bfr[n], acc[m][n], 0, 0, 0);
        }
        __syncthreads();
    }

    const int rbase = row0 + wr * 64 + (lane >> 4) * 4;
    const int cbase = wc * 64 + (lane & 15);
#pragma unroll
    for (int m = 0; m < 4; ++m)
#pragma unroll
        for (int n = 0; n < 4; ++n)
#pragma unroll
            for (int j = 0; j < 4; ++j) {
                int r = rbase + m * 16 + j;
                int c = cbase + n * 16;
                if (r < BN) proj[(size_t)r * CC + c] = f2bf(acc[m][n][j]);
            }
}

// ---------------------------------------------------------------------------
// Kernel S: combined grid. Blocks [0, NB): single-pass decoupled-lookback
// scan of deg -> cursor. Blocks [NB, NB+SCB): per-node scores from proj.
// ---------------------------------------------------------------------------
__global__ __launch_bounds__(256) void k_scanscore(
    const int* __restrict__ deg, unsigned long long* __restrict__ st,
    int* __restrict__ cursor, const unsigned short* __restrict__ proj,
    const float* __restrict__ a_src, const float* __restrict__ a_trg,
    float* __restrict__ ssrc, float* __restrict__ strg)
{
    const int t = threadIdx.x;

    if (blockIdx.x >= NB) {
        // ---- score path: node = sblk*32 + t>>3, head = t&7
        __shared__ float sa[CC], sb[CC];
        sa[t] = a_src[t];
        sb[t] = a_trg[t];
        __syncthreads();
        int sblk = blockIdx.x - NB;
        int node = sblk * 32 + (t >> 3);
        int h    = t & 7;
        const uint4* q4 = (const uint4*)(proj + (size_t)node * CC + h * 32);
        const float* pa = sa + h * 32;
        const float* pb = sb + h * 32;
        float vs = 0.f, vt = 0.f;
#pragma unroll
        for (int i = 0; i < 4; ++i) {
            uint4 q = q4[i];
            unsigned int v[4] = {q.x, q.y, q.z, q.w};
#pragma unroll
            for (int j = 0; j < 4; ++j) {
                float lo = __uint_as_float(v[j] << 16);
                float hi = __uint_as_float(v[j] & 0xffff0000u);
                int c = i * 8 + j * 2;
                vs += lo * pa[c] + hi * pa[c + 1];
                vt += lo * pb[c] + hi * pb[c + 1];
            }
        }
        ssrc[(size_t)node * HH + h] = vs;
        strg[(size_t)node * HH + h] = vt;
        return;
    }

    // ---- scan path (decoupled look-back, validated R11-R13)
    __shared__ int w4b[4];
    __shared__ int sh_boff;
    const int bid = blockIdx.x;
    const int i = bid * 256 + t;
    int v = (i < BN) ? deg[i] : 0;

    int total;
    int excl = block_excl_scan_256(v, t, w4b, &total);

    if (t < 64) {
        if (t == 0) {
            unsigned long long pub =
                ((bid == 0 ? 2ull : 1ull) << 32) | (unsigned int)total;
            __hip_atomic_store(&st[bid], pub, __ATOMIC_RELEASE,
                               __HIP_MEMORY_SCOPE_AGENT);
        }
        int boff = 0;
        if (bid > 0) {
            int j = bid - 1;
            while (true) {
                int idx = j - t;
                unsigned long long s = (idx >= 0)
                    ? __hip_atomic_load(&st[idx], __ATOMIC_ACQUIRE,
                                        __HIP_MEMORY_SCOPE_AGENT)
                    : (2ull << 32);                       // virtual prefix 0
                int flag = (int)(s >> 32);
                unsigned long long pend = __ballot(flag == 0);
                unsigned long long pref = __ballot(flag == 2);
                int fp  = pref ? (__ffsll(pref) - 1) : 64;
                int fpd = pend ? (__ffsll(pend) - 1) : 64;
                if (fp < fpd) {
                    int val = (t <= fp) ? (int)(s & 0xffffffffu) : 0;
#pragma unroll
                    for (int off = 32; off >= 1; off >>= 1)
                        val += __shfl_xor(val, off);
                    boff += val;
                    break;
                } else if (fpd == 64) {                    // 64 aggregates
                    int val = (int)(s & 0xffffffffu);
#pragma unroll
                    for (int off = 32; off >= 1; off >>= 1)
                        val += __shfl_xor(val, off);
                    boff += val;
                    j -= 64;
                } else {
                    __builtin_amdgcn_s_sleep(2);           // pending: retry
                }
            }
            if (t == 0) {
                unsigned long long pub =
                    (2ull << 32) | (unsigned int)(boff + total);
                __hip_atomic_store(&st[bid], pub, __ATOMIC_RELEASE,
                                   __HIP_MEMORY_SCOPE_AGENT);
            }
        }
        if (t == 0) sh_boff = boff;
    }
    __syncthreads();
    if (i < BN) cursor[i] = sh_boff + excl;
}

// ---------------------------------------------------------------------------
// Kernel C: 8 edges/thread, coalesced loads, 8 independent atomic chains;
// single 4B scattered store per edge (src | mask-bit).
// ---------------------------------------------------------------------------
__global__ __launch_bounds__(256) void k_edge(
    const int* __restrict__ ei, const float* __restrict__ mask,
    int* __restrict__ cursor, int* __restrict__ esrc)
{
    int i = blockIdx.x * 256 + threadIdx.x;     // [0, BE/8)
    if (i >= BE / 8) return;
    int e0 = i * 8;
    int b  = e0 / EE;                            // EE%8==0 -> uniform batch
    int le = e0 - b * EE;
    const int* eb = ei + (size_t)b * 2 * EE;
    int4   sq0 = *(const int4*)(eb + le);
    int4   sq1 = *(const int4*)(eb + le + 4);
    int4   tq0 = *(const int4*)(eb + EE + le);
    int4   tq1 = *(const int4*)(eb + EE + le + 4);
    float4 mq0 = *(const float4*)(mask + e0);
    float4 mq1 = *(const float4*)(mask + e0 + 4);
    int base = b * NN;

    int p0 = atomicAdd(&cursor[tq0.x + base], 1);
    int p1 = atomicAdd(&cursor[tq0.y + base], 1);
    int p2 = atomicAdd(&cursor[tq0.z + base], 1);
    int p3 = atomicAdd(&cursor[tq0.w + base], 1);
    int p4 = atomicAdd(&cursor[tq1.x + base], 1);
    int p5 = atomicAdd(&cursor[tq1.y + base], 1);
    int p6 = atomicAdd(&cursor[tq1.z + base], 1);
    int p7 = atomicAdd(&cursor[tq1.w + base], 1);
    esrc[p0] = (sq0.x + base) | (mq0.x > 0.f ? 0 : (int)0x80000000);
    esrc[p1] = (sq0.y + base) | (mq0.y > 0.f ? 0 : (int)0x80000000);
    esrc[p2] = (sq0.z + base) | (mq0.z > 0.f ? 0 : (int)0x80000000);
    esrc[p3] = (sq0.w + base) | (mq0.w > 0.f ? 0 : (int)0x80000000);
    esrc[p4] = (sq1.x + base) | (mq1.x > 0.f ? 0 : (int)0x80000000);
    esrc[p5] = (sq1.y + base) | (mq1.y > 0.f ? 0 : (int)0x80000000);
    esrc[p6] = (sq1.z + base) | (mq1.z > 0.f ? 0 : (int)0x80000000);
    esrc[p7] = (sq1.w + base) | (mq1.w > 0.f ? 0 : (int)0x80000000);
}

// ---------------------------------------------------------------------------
// Kernel D: one wave per target node, 8 edges/step + depth-2 prefetch of the
// next group's esrc/ssrc chain. Lane l owns exp for (edge l&7, head l>>3);
// __shfl distributes. Own-lane den + 3-shuffle reduce.  (R13 verbatim)
// ---------------------------------------------------------------------------
__global__ __launch_bounds__(256) void k_gather(
    const int* __restrict__ cursor, const int* __restrict__ esrc,
    const float* __restrict__ ssrc, const float* __restrict__ strg,
    const unsigned short* __restrict__ proj, const float* __restrict__ bias,
    float* __restrict__ out)
{
    int gid  = blockIdx.x * 256 + threadIdx.x;
    int node = gid >> 6;
    int lane = gid & 63;
    if (node >= BN) return;
    int h  = lane >> 3;
    int el = lane & 7;
    int hb = lane & 56;
    float st = strg[(size_t)node * HH + h];
    int lo = node ? cursor[node - 1] : 0;
    int hi = cursor[node];

    const char* projc = (const char*)proj;
    const unsigned lb = lane * 8u;               // lane byte offset in row

    float acc0 = 0.f, acc1 = 0.f, acc2 = 0.f, acc3 = 0.f, deno = 0.f;

    // prologue: group 0's chain
    int  i0 = lo + el;
    bool v0 = i0 < hi;
    int  sv = v0 ? esrc[i0] : 0;
    int  s  = sv & 0x7fffffff;
    float f = ssrc[(size_t)s * HH + h];

    for (int p = lo; p < hi; p += 8) {
        int  i1 = p + 8 + el;
        bool v1 = i1 < hi;
        int  svn = v1 ? esrc[i1] : 0;
        float fn = ssrc[(size_t)(svn & 0x7fffffff) * HH + h];

        float c = f + st;
        c = c > 0.f ? c : 0.2f * c;                // leaky_relu(0.2)
        float ex = (v0 && sv >= 0) ? __expf(c) : 0.f;
        deno += ex;                                 // own-lane edge only

#pragma unroll
        for (int e = 0; e < 8; ++e) {
            float ee = __shfl(ex, e | hb);          // (edge e, this head)
            int   se = __shfl(s, e);
            ushort4 q = *(const ushort4*)(projc + (((unsigned)se << 9) + lb));
            acc0 += bf2f(q.x) * ee;
            acc1 += bf2f(q.y) * ee;
            acc2 += bf2f(q.z) * ee;
            acc3 += bf2f(q.w) * ee;
        }
        sv = svn; s = svn & 0x7fffffff; f = fn; v0 = v1;
    }

#pragma unroll
    for (int off = 1; off < 8; off <<= 1) deno += __shfl_xor(deno, off);

    float inv = 1.f / (deno + 1e-16f);
    float4 bv = ((const float4*)bias)[lane];
    float o0 = acc0 * inv + bv.x, o1 = acc1 * inv + bv.y;
    float o2 = acc2 * inv + bv.z, o3 = acc3 * inv + bv.w;
    o0 = o0 > 0.f ? o0 : __expf(o0) - 1.f;
    o1 = o1 > 0.f ? o1 : __expf(o1) - 1.f;
    o2 = o2 > 0.f ? o2 : __expf(o2) - 1.f;
    o3 = o3 > 0.f ? o3 : __expf(o3) - 1.f;
    ((float4*)(out + (size_t)node * CC))[lane] = make_float4(o0, o1, o2, o3);
}

// ---------------------------------------------------------------------------
extern "C" void kernel_launch(void* const* d_in, const int* in_sizes, int n_in,
                              void* d_out, int out_size, void* d_ws, size_t ws_size,
                              hipStream_t stream)
{
    const float* x     = (const float*)d_in[0];
    const int*   ei    = (const int*)  d_in[1];
    const float* mask  = (const float*)d_in[2];
    const float* Wm    = (const float*)d_in[3];
    const float* a_src = (const float*)d_in[4];
    const float* a_trg = (const float*)d_in[5];
    const float* bias  = (const float*)d_in[6];
    float* out = (float*)d_out;

    char* ws = (char*)d_ws;
    size_t off = 0;
    unsigned short* proj = (unsigned short*)(ws + off); off += (size_t)BN * CC * 2;// 20.48 MB
    float* ssrc = (float*)(ws + off); off += (size_t)BN * HH * 4;                  //  1.28 MB
    float* strg = (float*)(ws + off); off += (size_t)BN * HH * 4;                  //  1.28 MB
    int*   deg  = (int*)  (ws + off); off += (size_t)BN * 4;                       //  0.16 MB
    unsigned long long* st = (unsigned long long*)(ws + off); off += 256 * 8;      //  look-back state
    int*   cursor = (int*)(ws + off); off += (size_t)BN * 4;                       //  0.16 MB
    int*   esrc   = (int*)(ws + off); off += (size_t)(BE + 64) * 4;                //  2.56 MB

    // one memset covers deg + st (contiguous)
    hipMemsetAsync(deg, 0, (size_t)BN * 4 + 256 * 8, stream);
    k_gemmhist <<<GMB + HSB, 512, 0, stream>>>(x, Wm, ei, proj, deg);
    k_scanscore<<<NB + SCB, 256, 0, stream>>>(deg, st, cursor, proj,
                                              a_src, a_trg, ssrc, strg);
    k_edge     <<<(BE / 8 + 255) / 256, 256, 0, stream>>>(ei, mask, cursor, esrc);
    k_gather   <<<(BN * 64) / 256, 256, 0, stream>>>(cursor, esrc, ssrc, strg,
                                                     proj, bias, out);
}